// Round 14
// baseline (110.878 us; speedup 1.0000x reference)
//
#include <hip/hip_runtime.h>
#include <math.h>

#define NB 32
#define QQ 100
#define CC 256
#define HH 8
#define DH 32
#define SM 101   // kv rows per batch (100 points + mean)
#define TT 200   // branch queries per batch
#define TB 400   // both branches
#define PW 768   // P_all row width (q|k|v projections)

typedef __attribute__((ext_vector_type(8))) short s16x8;
typedef __attribute__((ext_vector_type(4))) float f32x4;

// RNE bf16
__device__ inline unsigned short f2bf(float x) {
    unsigned u = __float_as_uint(x);
    return (unsigned short)((u + 0x7fffu + ((u >> 16) & 1u)) >> 16);
}
__device__ inline float bf2f(unsigned short h) {
    return __uint_as_float(((unsigned)h) << 16);
}
// RNE split: hi = RNE(x), lo = RNE(x - hi); unbiased residual
__device__ inline ushort2 rsplit(float x) {
    ushort2 r;
    r.x = f2bf(x);
    r.y = f2bf(x - bf2f(r.x));
    return r;
}

// ---------------- meanF + stage-A far point ----------------
__global__ __launch_bounds__(256)
void meanfar0(const float* __restrict__ hs, float* __restrict__ meanF,
              int* __restrict__ far0) {
    int n = blockIdx.x;
    int c = threadIdx.x;
    const float* h = hs + (size_t)n * QQ * CC;
    float s = 0.f;
    for (int q = 0; q < QQ; ++q) s += h[q * CC + c];
    float c1 = s * 0.01f;
    meanF[(size_t)n * CC + c] = c1;
    __shared__ float c1s[CC];
    __shared__ float dls[QQ];
    c1s[c] = c1;
    __syncthreads();
    int wave = c >> 6, lane = c & 63;
    for (int q = wave; q < QQ; q += 4) {
        float p = 0.f;
        for (int cc = lane; cc < CC; cc += 64) {
            float d = c1s[cc] - h[q * CC + cc];
            p += d * d;
        }
        for (int off = 32; off > 0; off >>= 1) p += __shfl_down(p, off);
        if (lane == 0) dls[q] = p;
    }
    __syncthreads();
    if (c == 0) {
        int best = 0; float bv = dls[0];
        for (int q = 1; q < QQ; ++q) if (dls[q] > bv) { bv = dls[q]; best = q; }
        far0[n] = best;
    }
}

// ---------------- fused projection GEMM + Gram strips, one launch ----------------
#define LDK 40
#define GEMM_BX 26   // ceil(3232/128)
#define GEMM_BY 6    // 768/128
#define GEMM_NBLK (GEMM_BX * GEMM_BY)
__global__ __launch_bounds__(256, 2)
void projgram(const float* __restrict__ hs, const float* __restrict__ meanF,
              const float* __restrict__ W_g, const float* __restrict__ bias,
              float* __restrict__ out, float* __restrict__ G) {
    __shared__ unsigned short u16buf[4 * 128 * LDK];   // 40 KB, shared by both paths
    int tid = threadIdx.x;
    int lane = tid & 63, wave = tid >> 6;
    int fr = lane & 15, kb = lane >> 4;
    if (blockIdx.x < GEMM_NBLK) {
        unsigned short* Ahs = u16buf;
        unsigned short* Als = u16buf + 128 * LDK;
        unsigned short* Bhs = u16buf + 2 * 128 * LDK;
        unsigned short* Bls = u16buf + 3 * 128 * LDK;
        const int M = NB * SM;
        int bm = (blockIdx.x % GEMM_BX) * 128, bn = (blockIdx.x / GEMM_BX) * 128;
        int wm = (wave >> 1) * 64, wn = (wave & 1) * 64;
        int srow = tid >> 1, scol = (tid & 1) * 16;
        int am = bm + srow; if (am >= M) am = M - 1;
        int an = am / SM, ar = am - an * SM;
        const float* pA = (ar < QQ) ? hs + ((size_t)an * QQ + ar) * CC + scol
                                    : meanF + (size_t)an * CC + scol;
        const float* pW = W_g + (size_t)(bn + srow) * CC + scol;
        f32x4 acc[4][4];
#pragma unroll
        for (int mi = 0; mi < 4; ++mi)
#pragma unroll
            for (int ni = 0; ni < 4; ++ni)
                acc[mi][ni] = (f32x4){0.f, 0.f, 0.f, 0.f};
        for (int k0 = 0; k0 < CC; k0 += 32) {
            float4 av[4], wv[4];
#pragma unroll
            for (int j = 0; j < 4; ++j) {
                av[j] = *(const float4*)(pA + k0 + 4 * j);
                wv[j] = *(const float4*)(pW + k0 + 4 * j);
            }
            __syncthreads();
#pragma unroll
            for (int j = 0; j < 4; ++j) {
                ushort2 sx = rsplit(av[j].x), sy = rsplit(av[j].y), sz = rsplit(av[j].z), sw = rsplit(av[j].w);
                ushort4 h4; h4.x = sx.x; h4.y = sy.x; h4.z = sz.x; h4.w = sw.x;
                ushort4 l4; l4.x = sx.y; l4.y = sy.y; l4.z = sz.y; l4.w = sw.y;
                *(ushort4*)&Ahs[srow * LDK + scol + 4 * j] = h4;
                *(ushort4*)&Als[srow * LDK + scol + 4 * j] = l4;
                ushort2 tx = rsplit(wv[j].x), ty = rsplit(wv[j].y), tz = rsplit(wv[j].z), tw = rsplit(wv[j].w);
                ushort4 wh4; wh4.x = tx.x; wh4.y = ty.x; wh4.z = tz.x; wh4.w = tw.x;
                ushort4 wl4; wl4.x = tx.y; wl4.y = ty.y; wl4.z = tz.y; wl4.w = tw.y;
                *(ushort4*)&Bhs[srow * LDK + scol + 4 * j] = wh4;
                *(ushort4*)&Bls[srow * LDK + scol + 4 * j] = wl4;
            }
            __syncthreads();
            s16x8 fah[4], fal[4], fbh[4], fbl[4];
#pragma unroll
            for (int mi = 0; mi < 4; ++mi) {
                fah[mi] = *(const s16x8*)&Ahs[(wm + mi * 16 + fr) * LDK + kb * 8];
                fal[mi] = *(const s16x8*)&Als[(wm + mi * 16 + fr) * LDK + kb * 8];
            }
#pragma unroll
            for (int ni = 0; ni < 4; ++ni) {
                fbh[ni] = *(const s16x8*)&Bhs[(wn + ni * 16 + fr) * LDK + kb * 8];
                fbl[ni] = *(const s16x8*)&Bls[(wn + ni * 16 + fr) * LDK + kb * 8];
            }
#pragma unroll
            for (int mi = 0; mi < 4; ++mi)
#pragma unroll
                for (int ni = 0; ni < 4; ++ni) {
                    acc[mi][ni] = __builtin_amdgcn_mfma_f32_16x16x32_bf16(fah[mi], fbh[ni], acc[mi][ni], 0, 0, 0);
                    acc[mi][ni] = __builtin_amdgcn_mfma_f32_16x16x32_bf16(fah[mi], fbl[ni], acc[mi][ni], 0, 0, 0);
                    acc[mi][ni] = __builtin_amdgcn_mfma_f32_16x16x32_bf16(fal[mi], fbh[ni], acc[mi][ni], 0, 0, 0);
                }
        }
#pragma unroll
        for (int mi = 0; mi < 4; ++mi) {
            int mb = bm + wm + mi * 16 + kb * 4;
#pragma unroll
            for (int r = 0; r < 4; ++r) {
                int m = mb + r;
                if (m < M) {
#pragma unroll
                    for (int ni = 0; ni < 4; ++ni) {
                        int col = bn + wn + ni * 16 + fr;
                        out[(size_t)m * PW + col] = acc[mi][ni][r] + bias[col];
                    }
                }
            }
        }
    } else {
        int bi = blockIdx.x - GEMM_NBLK;
        int ti = bi % 7, n = bi / 7;
        unsigned short* Ah = u16buf;
        unsigned short* Al = u16buf + 112 * LDK;
        const float* hb = hs + (size_t)n * QQ * CC;
        const float* mb = meanF + (size_t)n * CC;
        f32x4 acc[2];
        acc[0] = (f32x4){0.f, 0.f, 0.f, 0.f};
        acc[1] = (f32x4){0.f, 0.f, 0.f, 0.f};
        int tj0 = wave, tj1 = wave + 4;
        for (int k0 = 0; k0 < CC; k0 += 32) {
            __syncthreads();
            if (tid < 224) {
                int row = tid >> 1, kk = (tid & 1) * 16;
                float4 v[4];
                if (row < SM) {
                    const float* rp = (row < QQ) ? hb + (size_t)row * CC : mb;
#pragma unroll
                    for (int j = 0; j < 4; ++j) v[j] = *(const float4*)(rp + k0 + kk + 4 * j);
                } else {
#pragma unroll
                    for (int j = 0; j < 4; ++j) v[j] = (float4){0.f, 0.f, 0.f, 0.f};
                }
#pragma unroll
                for (int j = 0; j < 4; ++j) {
                    ushort2 sx = rsplit(v[j].x), sy = rsplit(v[j].y), sz = rsplit(v[j].z), sw = rsplit(v[j].w);
                    ushort4 h4; h4.x = sx.x; h4.y = sy.x; h4.z = sz.x; h4.w = sw.x;
                    ushort4 l4; l4.x = sx.y; l4.y = sy.y; l4.z = sz.y; l4.w = sw.y;
                    *(ushort4*)&Ah[row * LDK + kk + 4 * j] = h4;
                    *(ushort4*)&Al[row * LDK + kk + 4 * j] = l4;
                }
            }
            __syncthreads();
            s16x8 ah = *(const s16x8*)&Ah[(ti * 16 + fr) * LDK + kb * 8];
            s16x8 al = *(const s16x8*)&Al[(ti * 16 + fr) * LDK + kb * 8];
            {
                s16x8 bh = *(const s16x8*)&Ah[(tj0 * 16 + fr) * LDK + kb * 8];
                s16x8 bl = *(const s16x8*)&Al[(tj0 * 16 + fr) * LDK + kb * 8];
                acc[0] = __builtin_amdgcn_mfma_f32_16x16x32_bf16(ah, bh, acc[0], 0, 0, 0);
                acc[0] = __builtin_amdgcn_mfma_f32_16x16x32_bf16(ah, bl, acc[0], 0, 0, 0);
                acc[0] = __builtin_amdgcn_mfma_f32_16x16x32_bf16(al, bh, acc[0], 0, 0, 0);
            }
            if (tj1 < 7) {
                s16x8 bh = *(const s16x8*)&Ah[(tj1 * 16 + fr) * LDK + kb * 8];
                s16x8 bl = *(const s16x8*)&Al[(tj1 * 16 + fr) * LDK + kb * 8];
                acc[1] = __builtin_amdgcn_mfma_f32_16x16x32_bf16(ah, bh, acc[1], 0, 0, 0);
                acc[1] = __builtin_amdgcn_mfma_f32_16x16x32_bf16(ah, bl, acc[1], 0, 0, 0);
                acc[1] = __builtin_amdgcn_mfma_f32_16x16x32_bf16(al, bh, acc[1], 0, 0, 0);
            }
        }
        float* Gn = G + (size_t)n * SM * 104;
#pragma unroll
        for (int u = 0; u < 2; ++u) {
            int tj = u ? tj1 : tj0;
            if (tj >= 7) continue;
#pragma unroll
            for (int r = 0; r < 4; ++r) {
                int m = ti * 16 + kb * 4 + r;
                int col = tj * 16 + fr;
                if (m < SM && col < SM) Gn[(size_t)m * 104 + col] = (u ? acc[1] : acc[0])[r];
            }
        }
    }
}

// ---------------- selB: farsel (blocks 0..31) | stage-B SMHA (blocks 32..63) ----------------
__global__ __launch_bounds__(512)
void selB(const float* __restrict__ G, const float* __restrict__ P_all,
          const int* __restrict__ far0, const float* __restrict__ ow,
          const float* __restrict__ ob, float* __restrict__ Psum0,
          int* __restrict__ far_rm, int* __restrict__ far_md,
          float* __restrict__ out_assign, float* __restrict__ out_sidx,
          float* __restrict__ out_didx, float* __restrict__ cd,
          float* __restrict__ cs) {
    int tid = threadIdx.x;
    if (blockIdx.x < NB) {
        int n = blockIdx.x;
        __shared__ float sumdot[104], meandot[104], norm[104];
        __shared__ float psumP[2][CC];
        const float* Gn = G + (size_t)n * SM * 104;
        {
            int c = tid & 255, half = tid >> 8;
            const float* basep = P_all + (size_t)n * SM * PW + c;
            float accp = 0.f;
            for (int q = half * 50; q < half * 50 + 50; ++q) accp += basep[(size_t)q * PW];
            psumP[half][c] = accp;
        }
        if (tid < SM) {
            const float* row = Gn + (size_t)tid * 104;
            float a = 0.f;
            for (int q = 0; q < QQ; ++q) a += row[q];
            sumdot[tid] = a; meandot[tid] = row[QQ]; norm[tid] = row[tid];
        }
        __syncthreads();
        if (tid < 256) Psum0[(size_t)n * CC + tid] = psumP[0][tid] + psumP[1][tid];
        if (tid < QQ) {
            int q = tid, qm1 = (q + QQ - 1) % QQ;
            const float* gq = Gn + (size_t)qm1 * 104;
            int best = -1; float bv = -1e30f;
            for (int s = 0; s < QQ; ++s) {
                if (s == qm1) continue;
                float val = norm[s] - (sumdot[s] - gq[s]) * (2.f / 99.f);
                if (val > bv) { bv = val; best = s; }
            }
            far_rm[n * QQ + q] = best;
        } else if (tid >= 128 && tid < 128 + QQ) {
            int q = tid - 128, qm1 = (q + QQ - 1) % QQ;
            const float* gq = Gn + (size_t)qm1 * 104;
            int best = -1; float bv = -1e30f;
            for (int s = 0; s < SM; ++s) {
                if (s == qm1) continue;
                float val = norm[s] - (sumdot[s] - gq[s] + meandot[s]) * (2.f / 100.f);
                if (val > bv) { bv = val; best = s; }
            }
            far_md[n * QQ + q] = best;
        }
    } else {
        int n = blockIdx.x - NB;
        int h = tid >> 6, lane = tid & 63;
        __shared__ float at[HH][2][104];
        __shared__ float qsh[HH][2][DH];
        __shared__ float rsh[HH][2];
        __shared__ float pvs[2][CC];
        __shared__ int sdi[2];
        const float* base = P_all + (size_t)n * SM * PW;
        if (lane < 2 * DH) {
            int t = lane >> 5, d = lane & 31;
            int row = t ? far0[n] : QQ;
            qsh[h][t][d] = base[(size_t)row * PW + h * DH + d];
        }
        const float scl = 0.17677669529663687f;
        float p0 = 0.f, p1 = 0.f;
        for (int s = lane; s < 104; s += 64) {
            float a0v = 0.f, a1v = 0.f;
            if (s < QQ) {
                const float4* kr = (const float4*)(base + (size_t)s * PW + CC + h * DH);
                float d0 = 0.f, d1 = 0.f;
#pragma unroll
                for (int j = 0; j < 8; ++j) {
                    float4 k4 = kr[j];
                    d0 += qsh[h][0][4 * j] * k4.x + qsh[h][0][4 * j + 1] * k4.y
                        + qsh[h][0][4 * j + 2] * k4.z + qsh[h][0][4 * j + 3] * k4.w;
                    d1 += qsh[h][1][4 * j] * k4.x + qsh[h][1][4 * j + 1] * k4.y
                        + qsh[h][1][4 * j + 2] * k4.z + qsh[h][1][4 * j + 3] * k4.w;
                }
                a0v = 1.f / (1.f + __expf(-d0 * scl));
                a1v = 1.f / (1.f + __expf(-d1 * scl));
                p0 += a0v; p1 += a1v;
            }
            at[h][0][s] = a0v;
            at[h][1][s] = a1v;
        }
#pragma unroll
        for (int off = 32; off > 0; off >>= 1) {
            p0 += __shfl_down(p0, off);
            p1 += __shfl_down(p1, off);
        }
        // broadcast BOTH totals from lane 0 (fix: lane 0 holds both reduced sums)
        float p0t = __shfl(p0, 0);
        float p1t = __shfl(p1, 0);
        if (lane == 0) { rsh[h][0] = p0; rsh[h][1] = p1; }
        {
            int t = lane >> 5, d = lane & 31;
            float rv = t ? p1t : p0t;
            float inv = 1.f / (rv + 1e-4f);
            float acc = 0.f;
            const float* vb = base + 2 * CC + h * DH + d;
            for (int s = 0; s < QQ; ++s) acc += at[h][t][s] * vb[(size_t)s * PW];
            pvs[t][h * DH + d] = acc * inv;
        }
        __syncthreads();
        if (tid == 0) {
            float c0 = 0.f, c1v = 0.f;
            for (int h2 = 0; h2 < HH; ++h2) { c0 += rsh[h2][0]; c1v += rsh[h2][1]; }
            int si = (c1v < c0) ? 1 : 0;
            int di = (c1v > c0) ? 1 : 0;
            sdi[0] = si; sdi[1] = di;
            out_sidx[n] = (float)si;
            out_didx[n] = (float)di;
        }
        __syncthreads();
        if (tid < 2 * QQ) {
            int t = tid / QQ, s = tid % QQ;
            float m = 0.f;
#pragma unroll
            for (int h2 = 0; h2 < HH; ++h2) m += at[h2][t][s];
            out_assign[(size_t)n * 2 * QQ + tid] = m * 0.125f;
        }
        {
            int t = tid >> 8, c = tid & 255;
            const float4* wr4 = (const float4*)(ow + (size_t)c * CC);
            const float4* pz = (const float4*)&pvs[t][0];
            float a = ob[c];
#pragma unroll 8
            for (int k = 0; k < 64; ++k) {
                float4 w = wr4[k], x = pz[k];
                a += x.x * w.x + x.y * w.y + x.z * w.z + x.w * w.w;
            }
            if (t == sdi[1]) cd[(size_t)n * CC + c] = a;
            if (t == sdi[0]) cs[(size_t)n * CC + c] = a;
        }
    }
}

// ---------------- MFMA attention: one block per (n,h), 8 waves x 50 rows; pv out as bf16 hi/lo ----------------
__global__ __launch_bounds__(512)
void attn_mfma(const float* __restrict__ P_all, const float* __restrict__ Psum0,
               const int* __restrict__ far_rm, const int* __restrict__ far_md,
               unsigned short* __restrict__ pvh, unsigned short* __restrict__ pvl,
               float* __restrict__ rowsum) {
    int h = blockIdx.x, n = blockIdx.y;
    int tid = threadIdx.x;
    int w = tid >> 6, lane = tid & 63;
    int fr = lane & 15, hi = lane >> 4;
    int d0 = hi * 8;
    __shared__ unsigned short Kh[112 * 40];
    __shared__ unsigned short Kl[112 * 40];
    __shared__ unsigned short Vt[32 * 136];
    __shared__ unsigned short Pb[8][64 * 40];
    __shared__ float rsL[8][64];
    const float* base = P_all + (size_t)n * SM * PW;
    for (int idx = tid; idx < 112 * 8; idx += 512) {
        int key = idx >> 3, d4 = (idx & 7) * 4;
        float4 kv = {0.f, 0.f, 0.f, 0.f}, vv = {0.f, 0.f, 0.f, 0.f};
        if (key < SM) {
            kv = *(const float4*)&base[(size_t)key * PW + CC + h * DH + d4];
            vv = *(const float4*)&base[(size_t)key * PW + 2 * CC + h * DH + d4];
        }
        ushort2 sx = rsplit(kv.x), sy = rsplit(kv.y), sz = rsplit(kv.z), sw = rsplit(kv.w);
        ushort4 h4; h4.x = sx.x; h4.y = sy.x; h4.z = sz.x; h4.w = sw.x;
        ushort4 l4; l4.x = sx.y; l4.y = sy.y; l4.z = sz.y; l4.w = sw.y;
        *(ushort4*)&Kh[key * 40 + d4] = h4;
        *(ushort4*)&Kl[key * 40 + d4] = l4;
        Vt[(d4 + 0) * 136 + key] = f2bf(vv.x);
        Vt[(d4 + 1) * 136 + key] = f2bf(vv.y);
        Vt[(d4 + 2) * 136 + key] = f2bf(vv.z);
        Vt[(d4 + 3) * 136 + key] = f2bf(vv.w);
    }
    for (int idx = tid; idx < 32 * 16; idx += 512) {
        int d = idx >> 4, key = 112 + (idx & 15);
        Vt[d * 136 + key] = 0;
    }
    __syncthreads();
    const float* Psum0n = Psum0 + n * CC;
    int rowbase = w * 50;
    unsigned short* Pw = Pb[w];
    const float scl = 0.17677669529663687f;
    s16x8 qh[4], ql[4];
    int mk[4], sb[4];
#pragma unroll
    for (int qi = 0; qi < 4; ++qi) {
        int lq = qi * 16 + fr;
        int row = rowbase + (lq < 50 ? lq : 49);
        int b = row >= TT;
        int t = row - b * TT;
        int q = t >> 1;
        mk[qi] = q; sb[qi] = b ? SM : QQ;
        float qv[8];
        if (t & 1) {
            int f = (b ? far_md : far_rm)[n * QQ + q];
            const float4* pr = (const float4*)(base + (size_t)f * PW + h * DH + d0);
            float4 v0 = pr[0], v1 = pr[1];
            qv[0] = v0.x; qv[1] = v0.y; qv[2] = v0.z; qv[3] = v0.w;
            qv[4] = v1.x; qv[5] = v1.y; qv[6] = v1.z; qv[7] = v1.w;
        } else {
            int qm1 = (q + QQ - 1) % QQ;
            const float4* ps = (const float4*)(Psum0n + h * DH + d0);
            const float4* pm = (const float4*)(base + (size_t)qm1 * PW + h * DH + d0);
            const float4* pmn = (const float4*)(base + (size_t)QQ * PW + h * DH + d0);
            float invd = b ? 0.01f : (1.f / 99.f);
            float bb = b ? 1.f : 0.f;
            float4 a0 = ps[0], c0 = pm[0], m0 = pmn[0];
            float4 a1 = ps[1], c1 = pm[1], m1 = pmn[1];
            qv[0] = (a0.x - c0.x + bb * m0.x) * invd;
            qv[1] = (a0.y - c0.y + bb * m0.y) * invd;
            qv[2] = (a0.z - c0.z + bb * m0.z) * invd;
            qv[3] = (a0.w - c0.w + bb * m0.w) * invd;
            qv[4] = (a1.x - c1.x + bb * m1.x) * invd;
            qv[5] = (a1.y - c1.y + bb * m1.y) * invd;
            qv[6] = (a1.z - c1.z + bb * m1.z) * invd;
            qv[7] = (a1.w - c1.w + bb * m1.w) * invd;
        }
        s16x8 qhv, qlv;
#pragma unroll
        for (int j = 0; j < 8; ++j) {
            ushort2 sp = rsplit(qv[j]);
            qhv[j] = (short)sp.x;
            qlv[j] = (short)sp.y;
        }
        qh[qi] = qhv; ql[qi] = qlv;
    }
    f32x4 pvacc[4][2];
#pragma unroll
    for (int qi = 0; qi < 4; ++qi) {
        pvacc[qi][0] = (f32x4){0.f, 0.f, 0.f, 0.f};
        pvacc[qi][1] = (f32x4){0.f, 0.f, 0.f, 0.f};
    }
    float rs[4] = {0.f, 0.f, 0.f, 0.f};
#pragma unroll
    for (int kc = 0; kc < 4; ++kc) {
        int k0 = kc * 32;
        {
            s16x8 ah = *(const s16x8*)&Kh[(k0 + fr) * 40 + d0];
            s16x8 al = *(const s16x8*)&Kl[(k0 + fr) * 40 + d0];
#pragma unroll
            for (int qi = 0; qi < 4; ++qi) {
                f32x4 s0 = (f32x4){0.f, 0.f, 0.f, 0.f};
                s0 = __builtin_amdgcn_mfma_f32_16x16x32_bf16(ah, qh[qi], s0, 0, 0, 0);
                s0 = __builtin_amdgcn_mfma_f32_16x16x32_bf16(ah, ql[qi], s0, 0, 0, 0);
                s0 = __builtin_amdgcn_mfma_f32_16x16x32_bf16(al, qh[qi], s0, 0, 0, 0);
                int kb0 = k0 + 4 * hi;
                float a0 = (kb0 + 0 < sb[qi] && kb0 + 0 != mk[qi]) ? 1.f / (1.f + __expf(-s0[0] * scl)) : 0.f;
                float a1 = (kb0 + 1 < sb[qi] && kb0 + 1 != mk[qi]) ? 1.f / (1.f + __expf(-s0[1] * scl)) : 0.f;
                float a2 = (kb0 + 2 < sb[qi] && kb0 + 2 != mk[qi]) ? 1.f / (1.f + __expf(-s0[2] * scl)) : 0.f;
                float a3 = (kb0 + 3 < sb[qi] && kb0 + 3 != mk[qi]) ? 1.f / (1.f + __expf(-s0[3] * scl)) : 0.f;
                rs[qi] += a0 + a1 + a2 + a3;
                ushort4 p4;
                p4.x = f2bf(a0); p4.y = f2bf(a1); p4.z = f2bf(a2); p4.w = f2bf(a3);
                *(ushort4*)&Pw[(qi * 16 + fr) * 40 + 4 * hi] = p4;
            }
        }
        if (kc < 3) {
            s16x8 ah = *(const s16x8*)&Kh[(k0 + 16 + fr) * 40 + d0];
            s16x8 al = *(const s16x8*)&Kl[(k0 + 16 + fr) * 40 + d0];
#pragma unroll
            for (int qi = 0; qi < 4; ++qi) {
                f32x4 s1 = (f32x4){0.f, 0.f, 0.f, 0.f};
                s1 = __builtin_amdgcn_mfma_f32_16x16x32_bf16(ah, qh[qi], s1, 0, 0, 0);
                s1 = __builtin_amdgcn_mfma_f32_16x16x32_bf16(ah, ql[qi], s1, 0, 0, 0);
                s1 = __builtin_amdgcn_mfma_f32_16x16x32_bf16(al, qh[qi], s1, 0, 0, 0);
                int kb1 = k0 + 16 + 4 * hi;
                float a0 = (kb1 + 0 < sb[qi] && kb1 + 0 != mk[qi]) ? 1.f / (1.f + __expf(-s1[0] * scl)) : 0.f;
                float a1 = (kb1 + 1 < sb[qi] && kb1 + 1 != mk[qi]) ? 1.f / (1.f + __expf(-s1[1] * scl)) : 0.f;
                float a2 = (kb1 + 2 < sb[qi] && kb1 + 2 != mk[qi]) ? 1.f / (1.f + __expf(-s1[2] * scl)) : 0.f;
                float a3 = (kb1 + 3 < sb[qi] && kb1 + 3 != mk[qi]) ? 1.f / (1.f + __expf(-s1[3] * scl)) : 0.f;
                rs[qi] += a0 + a1 + a2 + a3;
                ushort4 p4;
                p4.x = f2bf(a0); p4.y = f2bf(a1); p4.z = f2bf(a2); p4.w = f2bf(a3);
                *(ushort4*)&Pw[(qi * 16 + fr) * 40 + 16 + 4 * hi] = p4;
            }
        } else {
            ushort4 z; z.x = 0; z.y = 0; z.z = 0; z.w = 0;
#pragma unroll
            for (int qi = 0; qi < 4; ++qi)
                *(ushort4*)&Pw[(qi * 16 + fr) * 40 + 16 + 4 * hi] = z;
        }
        s16x8 vb0 = *(const s16x8*)&Vt[(0 * 16 + fr) * 136 + k0 + d0];
        s16x8 vb1 = *(const s16x8*)&Vt[(1 * 16 + fr) * 136 + k0 + d0];
#pragma unroll
        for (int qi = 0; qi < 4; ++qi) {
            s16x8 pa = *(const s16x8*)&Pw[(qi * 16 + fr) * 40 + d0];
            pvacc[qi][0] = __builtin_amdgcn_mfma_f32_16x16x32_bf16(pa, vb0, pvacc[qi][0], 0, 0, 0);
            pvacc[qi][1] = __builtin_amdgcn_mfma_f32_16x16x32_bf16(pa, vb1, pvacc[qi][1], 0, 0, 0);
        }
    }
#pragma unroll
    for (int qi = 0; qi < 4; ++qi) {
        float r2 = rs[qi] + __shfl_xor(rs[qi], 16);
        r2 += __shfl_xor(r2, 32);
        int lq = qi * 16 + fr;
        if (hi == 0) {
            rsL[w][lq] = r2;
            if (lq < 50) rowsum[((size_t)n * HH + h) * TB + rowbase + lq] = r2;
        }
    }
#pragma unroll
    for (int qi = 0; qi < 4; ++qi) {
        float iv[4];
#pragma unroll
        for (int r = 0; r < 4; ++r) {
            int lq = qi * 16 + 4 * hi + r;
            iv[r] = 1.f / (rsL[w][lq] + 1e-4f);
        }
#pragma unroll
        for (int dt = 0; dt < 2; ++dt) {
#pragma unroll
            for (int r = 0; r < 4; ++r) {
                int lq = qi * 16 + 4 * hi + r;
                if (lq < 50) {
                    float x = pvacc[qi][dt][r] * iv[r];
                    ushort2 sp = rsplit(x);
                    size_t off = ((size_t)n * TB + rowbase + lq) * CC + h * DH + dt * 16 + fr;
                    pvh[off] = sp.x;
                    pvl[off] = sp.y;
                }
            }
        }
    }
}

// ---------------- fused out-projection + shift: 64 rows x 256 cols per block, 8 waves ----------------
__global__ __launch_bounds__(512)
void outshift(const unsigned short* __restrict__ pvh, const unsigned short* __restrict__ pvl,
              const float* __restrict__ ow, const float* __restrict__ ob,
              const float* __restrict__ cd, const float* __restrict__ cs,
              const float* __restrict__ rowsum,
              float* __restrict__ out_srm, float* __restrict__ out_smd) {
    __shared__ unsigned short Ahs[64][LDK], Als[64][LDK];
    __shared__ unsigned short Bhs[256][LDK], Bls[256][LDK];
    __shared__ float redcd[64][8], redcs[64][8];
    int tid = threadIdx.x;
    int lane = tid & 63, wave = tid >> 6;
    int wn = wave * 32;
    int fr = lane & 15, kb = lane >> 4;
    int bm = blockIdx.x * 64;
    int arow = tid >> 3, ak = (tid & 7) * 4;
    int brow = tid >> 1, bk = (tid & 1) * 16;
    const unsigned short* pAh = pvh + (size_t)(bm + arow) * CC + ak;
    const unsigned short* pAl = pvl + (size_t)(bm + arow) * CC + ak;
    const float* pB = ow + (size_t)brow * CC + bk;
    f32x4 acc[4][2];
#pragma unroll
    for (int mi = 0; mi < 4; ++mi)
#pragma unroll
        for (int ni = 0; ni < 2; ++ni)
            acc[mi][ni] = (f32x4){0.f, 0.f, 0.f, 0.f};
    for (int k0 = 0; k0 < CC; k0 += 32) {
        ushort4 ah4 = *(const ushort4*)(pAh + k0);
        ushort4 al4 = *(const ushort4*)(pAl + k0);
        float4 wv[4];
#pragma unroll
        for (int j = 0; j < 4; ++j) wv[j] = *(const float4*)(pB + k0 + 4 * j);
        __syncthreads();
        *(ushort4*)&Ahs[arow][ak] = ah4;
        *(ushort4*)&Als[arow][ak] = al4;
#pragma unroll
        for (int j = 0; j < 4; ++j) {
            ushort2 sx = rsplit(wv[j].x), sy = rsplit(wv[j].y), sz = rsplit(wv[j].z), sw = rsplit(wv[j].w);
            ushort4 h4; h4.x = sx.x; h4.y = sy.x; h4.z = sz.x; h4.w = sw.x;
            ushort4 l4; l4.x = sx.y; l4.y = sy.y; l4.z = sz.y; l4.w = sw.y;
            *(ushort4*)&Bhs[brow][bk + 4 * j] = h4;
            *(ushort4*)&Bls[brow][bk + 4 * j] = l4;
        }
        __syncthreads();
        s16x8 fah[4], fal[4], fbh[2], fbl[2];
#pragma unroll
        for (int mi = 0; mi < 4; ++mi) {
            fah[mi] = *(const s16x8*)&Ahs[mi * 16 + fr][kb * 8];
            fal[mi] = *(const s16x8*)&Als[mi * 16 + fr][kb * 8];
        }
#pragma unroll
        for (int ni = 0; ni < 2; ++ni) {
            fbh[ni] = *(const s16x8*)&Bhs[wn + ni * 16 + fr][kb * 8];
            fbl[ni] = *(const s16x8*)&Bls[wn + ni * 16 + fr][kb * 8];
        }
#pragma unroll
        for (int mi = 0; mi < 4; ++mi)
#pragma unroll
            for (int ni = 0; ni < 2; ++ni) {
                acc[mi][ni] = __builtin_amdgcn_mfma_f32_16x16x32_bf16(fah[mi], fbh[ni], acc[mi][ni], 0, 0, 0);
                acc[mi][ni] = __builtin_amdgcn_mfma_f32_16x16x32_bf16(fah[mi], fbl[ni], acc[mi][ni], 0, 0, 0);
                acc[mi][ni] = __builtin_amdgcn_mfma_f32_16x16x32_bf16(fal[mi], fbh[ni], acc[mi][ni], 0, 0, 0);
            }
    }
#pragma unroll
    for (int mi = 0; mi < 4; ++mi) {
#pragma unroll
        for (int r = 0; r < 4; ++r) {
            int lm = mi * 16 + kb * 4 + r;
            int g = bm + lm;
            int n = g / TB;
            float pcd = 0.f, pcs = 0.f;
#pragma unroll
            for (int ni = 0; ni < 2; ++ni) {
                int col = wn + ni * 16 + fr;
                float val = acc[mi][ni][r] + ob[col];
                float d1 = val - cd[(size_t)n * CC + col];
                float d2 = val - cs[(size_t)n * CC + col];
                pcd += d1 * d1;
                pcs += d2 * d2;
            }
#pragma unroll
            for (int m2 = 1; m2 < 16; m2 <<= 1) {
                pcd += __shfl_xor(pcd, m2);
                pcs += __shfl_xor(pcs, m2);
            }
            if (fr == 0) {
                redcd[lm][wave] = pcd;
                redcs[lm][wave] = pcs;
            }
        }
    }
    __syncthreads();
    if (tid < 32) {
        int g = bm + 2 * tid;
        int n = g / TB;
        int rem = g % TB;
        int b = rem / TT;
        int t = rem % TT;
        int q = t >> 1;
        float c0 = 0.f, c1v = 0.f;
        for (int h = 0; h < HH; ++h) {
            c0  += rowsum[((size_t)n * HH + h) * TB + rem];
            c1v += rowsum[((size_t)n * HH + h) * TB + rem + 1];
        }
        int si = (c1v < c0) ? 1 : 0;
        int di = (c1v > c0) ? 1 : 0;
        int ld = 2 * tid + di, ls = 2 * tid + si;
        float dd = 0.f, ds = 0.f;
#pragma unroll
        for (int wv2 = 0; wv2 < 8; ++wv2) { dd += redcd[ld][wv2]; ds += redcs[ls][wv2]; }
        (b ? out_smd : out_srm)[n * QQ + q] = sqrtf(dd + 1e-12f) + sqrtf(ds + 1e-12f);
    }
}

extern "C" void kernel_launch(void* const* d_in, const int* in_sizes, int n_in,
                              void* d_out, int out_size, void* d_ws, size_t ws_size,
                              hipStream_t stream) {
    const float* hs_pair = (const float*)d_in[0];
    const float* ipw = (const float*)d_in[1];
    const float* ipb = (const float*)d_in[2];
    const float* ow  = (const float*)d_in[3];
    const float* ob  = (const float*)d_in[4];
    const float* hs = hs_pair + (size_t)5 * NB * QQ * CC;  // hs_pair[-1]

    float* ws = (float*)d_ws;
    size_t o = 0;
    float* meanF   = ws + o; o += NB * CC;
    float* P_all   = ws + o; o += (size_t)NB * SM * PW;
    float* Psum0   = ws + o; o += NB * CC;
    float* G       = ws + o; o += (size_t)NB * SM * 104;
    int*   far0    = (int*)(ws + o); o += NB;
    int*   far_rm  = (int*)(ws + o); o += NB * QQ;
    int*   far_md  = (int*)(ws + o); o += NB * QQ;
    float* cd      = ws + o; o += NB * CC;
    float* cs      = ws + o; o += NB * CC;
    unsigned short* pvh = (unsigned short*)(ws + o); o += (size_t)NB * TB * CC / 2;
    unsigned short* pvl = (unsigned short*)(ws + o); o += (size_t)NB * TB * CC / 2;
    float* rowsum  = ws + o; o += (size_t)NB * HH * TB;
    if (o * sizeof(float) > ws_size) return;

    float* out = (float*)d_out;
    float* out_assign = out;
    float* out_sidx   = out + 6400;
    float* out_didx   = out + 6432;
    float* out_srm    = out + 6464;
    float* out_smd    = out + 9664;

    meanfar0<<<NB, 256, 0, stream>>>(hs, meanF, far0);
    projgram<<<GEMM_NBLK + 7 * NB, 256, 0, stream>>>(hs, meanF, ipw, ipb, P_all, G);
    selB<<<2 * NB, 512, 0, stream>>>(G, P_all, far0, ow, ob, Psum0, far_rm, far_md,
                                     out_assign, out_sidx, out_didx, cd, cs);
    attn_mfma<<<dim3(HH, NB), 512, 0, stream>>>(P_all, Psum0, far_rm, far_md, pvh, pvl, rowsum);
    outshift<<<NB * TB / 64, 512, 0, stream>>>(pvh, pvl, ow, ob, cd, cs, rowsum, out_srm, out_smd);
}